// Round 6
// baseline (9043.790 us; speedup 1.0000x reference)
//
#include <hip/hip_runtime.h>
#include <math.h>

// ESN recurrence: x_t = tanh(u_t @ w_in^T + w_bias + W @ h_{t-1}), h_0 = 0.
// B=8, T=4096, D_RES=1024, D_IN=64, fp32.
//
// R8: the sc0/XCC-ID fast-path kernel failed to produce a result twice
// (R6/R7) while R4/R5 ran cleanly -> treat those toolchain constructs as
// unsafe here and revert to proven primitives only (agent-scope relaxed
// atomics, DPP, ds_swizzle, s_sleep).
//
// Latency-hiding instead of latency-reduction: R5's ~3660cy step = ~800cy
// compute + ~2800cy of publish-visibility and stale-poll round trips at the
// Infinity Cache (agent-scope atomics bypass the non-coherent per-XCD L2s).
// The 8 batch recurrences are INDEPENDENT, and W is batch-independent, so
// each WG now serves the SAME 16-row chunk of W for TWO batches (A=2p,
// B=2p+1) and interleaves their steps in one instruction stream:
//   A phase: validate hvA -> stage LDS_A -> barrier -> ISSUE hvB loads ->
//            matvec A -> bfly -> tanh -> publish x_t(A) -> out
//   B phase: validate hvB -> stage LDS_B -> barrier -> ISSUE hvA loads ->
//            matvec B -> bfly -> tanh -> publish x_t(B) -> out
// Each batch's publish->validate window is a full opposite-phase compute
// (~700cy), so the IC round trip hides under the other batch's matvec.
// Loads are issued AFTER each barrier so the compiler's vmcnt-drain at
// s_barrier cannot serialize them; they are consumed one phase later.
// Weight registers HALVE (wreg[2][32]); per-thread FMA per super-iteration
// (one step of each batch) is unchanged (128).
//
// Geometry: 256 WGs = 64 chunks x 4 batch-pairs. Per batch: 64 WGs x 16
// rows. Per thread: 2 rows (rg=tid>>5 picks row pair, mc=tid&31 is k-lane).
//
// Protocol per batch (unchanged from R5): producer publishes each h element
// as one 8-byte relaxed agent atomic: hi32 = step tag (t+1), lo32 = float
// bits. Consumer loads each element once (4 u64/thread), spins rarely on
// its own 4 tags, stages into LDS (one buffer per batch; the WAR on LDS_A
// is separated by the B-phase barrier in program order), ONE barrier per
// phase. Butterfly reduce = R5's DPP+ds_swizzle hybrid. Per-row arithmetic
// is bit-identical to R5 -> absmax must stay 0.00390625.
//
// Safety: per batch, WG C publishes x_t only after consuming x_{t-1}; a
// producer overwrites a slot with x_{t+1} only after reading all of x_t,
// which requires every WG of that batch published x_t, which requires every
// WG consumed x_{t-1}. The A/B interleave only ADDS program-order
// constraints (a WG's A-publish also waits on its prior B-phase), which
// cannot enable an early overwrite; induction over (t, phase) shows
// progress (iter t's A phase completes once iter t-1 completed; t=0
// publishes are unconditional). Tags monotonic; hbuf zeroed per launch.

#define NB        8
#define T_STEPS   4096
#define DRES      1024
#define DIN       64
#define NTHREADS  256

typedef unsigned long long u64;

#define HBUF_BYTES (2 * NB * DRES * sizeof(u64))   // 128 KB, zeroed per launch

// Butterfly sum over 32 lanes, bit-identical to the 5-round __shfl_xor tree.
__device__ __forceinline__ float bfly32(float v) {
    v += __int_as_float(__builtin_amdgcn_update_dpp(
            0, __float_as_int(v), 0xB1, 0xF, 0xF, true));   // xor1 (quad_perm)
    v += __int_as_float(__builtin_amdgcn_update_dpp(
            0, __float_as_int(v), 0x4E, 0xF, 0xF, true));   // xor2 (quad_perm)
    v += __int_as_float(__builtin_amdgcn_update_dpp(
            0, __float_as_int(v), 0x141, 0xF, 0xF, true));  // xor4 via half_mirror
    v += __int_as_float(__builtin_amdgcn_update_dpp(
            0, __float_as_int(v), 0x140, 0xF, 0xF, true));  // xor8 via mirror
    v += __int_as_float(__builtin_amdgcn_ds_swizzle(
            __float_as_int(v), 0x401F));                    // xor16
    return v;
}

// Validate 4 tagged words against target tag; spin (rare) reloading only
// this thread's 4 elements. All indices compile-time -> stays in VGPRs.
__device__ __forceinline__ void validate4(u64 (&hv)[4], const u64* hs,
                                          unsigned tgt, int tid) {
    unsigned mn = 0xFFFFFFFFu;
    #pragma unroll
    for (int i = 0; i < 4; ++i) {
        const unsigned tg = (unsigned)(hv[i] >> 32);
        mn = tg < mn ? tg : mn;
    }
    int tries = 0;
    while (mn < tgt) {
        if (tries++ > 0) __builtin_amdgcn_s_sleep(1);
        mn = 0xFFFFFFFFu;
        #pragma unroll
        for (int i = 0; i < 4; ++i) {
            hv[i] = __hip_atomic_load(hs + tid + 256 * i,
                                      __ATOMIC_RELAXED, __HIP_MEMORY_SCOPE_AGENT);
            const unsigned tg = (unsigned)(hv[i] >> 32);
            mn = tg < mn ? tg : mn;
        }
    }
}

__launch_bounds__(NTHREADS, 1)
__global__ void esn_kernel(const float* __restrict__ u,      // [NB][T][DIN]
                           const float* __restrict__ w_in,   // [DRES][DIN]
                           const float* __restrict__ w,      // [DRES][DRES]
                           const float* __restrict__ w_bias, // [DRES]
                           float* __restrict__ out,          // [NB][T][DRES]
                           u64* __restrict__ hbuf)           // [2][NB][DRES] (tag|bits)
{
    const int tid   = threadIdx.x;
    const int pair  = (int)blockIdx.x & 3;          // batch pair (2p, 2p+1)
    const int chunk = (int)blockIdx.x >> 2;         // 0..63 row-chunk
    const int bA    = pair * 2;
    const int bB    = pair * 2 + 1;
    const int rg    = tid >> 5;                     // 0..7 row-group (2 rows each)
    const int mc    = tid & 31;                     // 0..31 k-lane
    const int row0  = chunk * 16 + rg * 2;          // first of this thread's 2 rows

    __shared__ float ldsA[DRES];                    // h stage for batch A
    __shared__ float ldsB[DRES];                    // h stage for batch B

    // ---- prologue: weights into registers (SHARED by both batches) ----
    float wreg[2][32];                              // wreg[i][j] = W[row0+i][mc+32j]
    #pragma unroll
    for (int i = 0; i < 2; ++i) {
        const float* wr = w + (size_t)(row0 + i) * DRES + mc;
        #pragma unroll
        for (int j = 0; j < 32; ++j) {
            wreg[i][j] = wr[32 * j];
        }
    }
    float win0[2], win1[2], bias[2];
    #pragma unroll
    for (int i = 0; i < 2; ++i) {
        win0[i] = w_in[(row0 + i) * DIN + 2 * mc];
        win1[i] = w_in[(row0 + i) * DIN + 2 * mc + 1];
        bias[i] = w_bias[row0 + i];
    }

    const float* uAp = u + (size_t)bA * T_STEPS * DIN;
    const float* uBp = u + (size_t)bB * T_STEPS * DIN;
    u64* const hA0 = hbuf + (size_t)bA * DRES;           // A slot, even t
    u64* const hA1 = hbuf + (size_t)(NB + bA) * DRES;    // A slot, odd t
    u64* const hB0 = hbuf + (size_t)bB * DRES;
    u64* const hB1 = hbuf + (size_t)(NB + bB) * DRES;

    float2 uAc = *(const float2*)(uAp + 2 * mc);    // u_0(A)
    float2 uBc = *(const float2*)(uBp + 2 * mc);    // u_0(B)

    u64 hvA[4], hvB[4];

    // ---- t = 0 peeled: h_0 = 0, recurrent term vanishes ----
    {
        // A
        float a0 = fmaf(win0[0], uAc.x, win1[0] * uAc.y);
        float a1 = fmaf(win0[1], uAc.x, win1[1] * uAc.y);
        a0 = bfly32(a0); a1 = bfly32(a1);
        const float za0 = a0 + bias[0], za1 = a1 + bias[1];
        const float xa0 = 1.0f - 2.0f / (__expf(2.0f * za0) + 1.0f);
        const float xa1 = 1.0f - 2.0f / (__expf(2.0f * za1) + 1.0f);
        if (mc < 2) {
            const float v = mc ? xa1 : xa0;
            __hip_atomic_store(hA0 + row0 + mc,
                               ((u64)1u << 32) | (u64)__float_as_uint(v),
                               __ATOMIC_RELAXED, __HIP_MEMORY_SCOPE_AGENT);
        }
        if (mc == 0) {
            *(float2*)(out + (size_t)bA * T_STEPS * DRES + row0) =
                make_float2(xa0, xa1);
        }
        // B
        float b0 = fmaf(win0[0], uBc.x, win1[0] * uBc.y);
        float b1 = fmaf(win0[1], uBc.x, win1[1] * uBc.y);
        b0 = bfly32(b0); b1 = bfly32(b1);
        const float zb0 = b0 + bias[0], zb1 = b1 + bias[1];
        const float xb0 = 1.0f - 2.0f / (__expf(2.0f * zb0) + 1.0f);
        const float xb1 = 1.0f - 2.0f / (__expf(2.0f * zb1) + 1.0f);
        if (mc < 2) {
            const float v = mc ? xb1 : xb0;
            __hip_atomic_store(hB0 + row0 + mc,
                               ((u64)1u << 32) | (u64)__float_as_uint(v),
                               __ATOMIC_RELAXED, __HIP_MEMORY_SCOPE_AGENT);
        }
        if (mc == 0) {
            *(float2*)(out + (size_t)bB * T_STEPS * DRES + row0) =
                make_float2(xb0, xb1);
        }
        // issue A's tagged loads for h_0(A) (validated at iter 1's A phase)
        #pragma unroll
        for (int i = 0; i < 4; ++i) {
            hvA[i] = __hip_atomic_load(hA0 + tid + 256 * i,
                                       __ATOMIC_RELAXED, __HIP_MEMORY_SCOPE_AGENT);
        }
        // prefetch u_1
        uAc = *(const float2*)(uAp + DIN + 2 * mc);
        uBc = *(const float2*)(uBp + DIN + 2 * mc);
    }

    #pragma unroll 1
    for (int t = 1; t < T_STEPS; ++t) {
        const int sp = (t - 1) & 1;                  // source slot parity
        u64* const hsA = sp ? hA1 : hA0;
        u64* const hpA = sp ? hA0 : hA1;
        u64* const hsB = sp ? hB1 : hB0;
        u64* const hpB = sp ? hB0 : hB1;
        const unsigned tgt = (unsigned)t;
        const int tn = (t + 1 < T_STEPS) ? (t + 1) : t;

        // ================= A phase =================
        validate4(hvA, hsA, tgt, tid);
        #pragma unroll
        for (int i = 0; i < 4; ++i) {
            ldsA[tid + 256 * i] = __uint_as_float((unsigned)hvA[i]);
        }
        __syncthreads();

        // issue B's tagged loads (h_{t-1}(B)); they fly under A's compute
        #pragma unroll
        for (int i = 0; i < 4; ++i) {
            hvB[i] = __hip_atomic_load(hsB + tid + 256 * i,
                                       __ATOMIC_RELAXED, __HIP_MEMORY_SCOPE_AGENT);
        }
        const float2 uAn = *(const float2*)(uAp + (size_t)tn * DIN + 2 * mc);

        {
            float a0 = fmaf(win0[0], uAc.x, win1[0] * uAc.y);
            float a1 = fmaf(win0[1], uAc.x, win1[1] * uAc.y);
            #pragma unroll
            for (int j = 0; j < 32; ++j) {
                const float hvf = ldsA[mc + 32 * j];
                a0 = fmaf(wreg[0][j], hvf, a0);
                a1 = fmaf(wreg[1][j], hvf, a1);
            }
            a0 = bfly32(a0); a1 = bfly32(a1);
            const float z0 = a0 + bias[0], z1 = a1 + bias[1];
            const float x0 = 1.0f - 2.0f / (__expf(2.0f * z0) + 1.0f);
            const float x1 = 1.0f - 2.0f / (__expf(2.0f * z1) + 1.0f);
            if (t + 1 < T_STEPS && mc < 2) {
                const float v = mc ? x1 : x0;
                __hip_atomic_store(hpA + row0 + mc,
                                   ((u64)(unsigned)(t + 1) << 32) |
                                   (u64)__float_as_uint(v),
                                   __ATOMIC_RELAXED, __HIP_MEMORY_SCOPE_AGENT);
            }
            if (mc == 0) {
                *(float2*)(out + ((size_t)bA * T_STEPS + t) * DRES + row0) =
                    make_float2(x0, x1);
            }
        }
        uAc = uAn;

        // ================= B phase =================
        validate4(hvB, hsB, tgt, tid);
        #pragma unroll
        for (int i = 0; i < 4; ++i) {
            ldsB[tid + 256 * i] = __uint_as_float((unsigned)hvB[i]);
        }
        __syncthreads();

        // issue A's tagged loads for h_t(A) (published one phase ago);
        // they fly under B's compute, validated at iter t+1's A phase
        if (t + 1 < T_STEPS) {
            #pragma unroll
            for (int i = 0; i < 4; ++i) {
                hvA[i] = __hip_atomic_load(hpA + tid + 256 * i,
                                           __ATOMIC_RELAXED,
                                           __HIP_MEMORY_SCOPE_AGENT);
            }
        }
        const float2 uBn = *(const float2*)(uBp + (size_t)tn * DIN + 2 * mc);

        {
            float b0 = fmaf(win0[0], uBc.x, win1[0] * uBc.y);
            float b1 = fmaf(win0[1], uBc.x, win1[1] * uBc.y);
            #pragma unroll
            for (int j = 0; j < 32; ++j) {
                const float hvf = ldsB[mc + 32 * j];
                b0 = fmaf(wreg[0][j], hvf, b0);
                b1 = fmaf(wreg[1][j], hvf, b1);
            }
            b0 = bfly32(b0); b1 = bfly32(b1);
            const float z0 = b0 + bias[0], z1 = b1 + bias[1];
            const float x0 = 1.0f - 2.0f / (__expf(2.0f * z0) + 1.0f);
            const float x1 = 1.0f - 2.0f / (__expf(2.0f * z1) + 1.0f);
            if (t + 1 < T_STEPS && mc < 2) {
                const float v = mc ? x1 : x0;
                __hip_atomic_store(hpB + row0 + mc,
                                   ((u64)(unsigned)(t + 1) << 32) |
                                   (u64)__float_as_uint(v),
                                   __ATOMIC_RELAXED, __HIP_MEMORY_SCOPE_AGENT);
            }
            if (mc == 0) {
                *(float2*)(out + ((size_t)bB * T_STEPS + t) * DRES + row0) =
                    make_float2(x0, x1);
            }
        }
        uBc = uBn;
    }
}

extern "C" void kernel_launch(void* const* d_in, const int* in_sizes, int n_in,
                              void* d_out, int out_size, void* d_ws, size_t ws_size,
                              hipStream_t stream) {
    const float* u      = (const float*)d_in[0];
    const float* w_in   = (const float*)d_in[1];
    const float* w      = (const float*)d_in[2];
    const float* w_bias = (const float*)d_in[3];
    float* out = (float*)d_out;
    u64* hbuf = (u64*)d_ws;

    // tags must start below 1 (ws is re-poisoned before every call)
    hipMemsetAsync(hbuf, 0, HBUF_BYTES, stream);

    esn_kernel<<<NB * 32, NTHREADS, 0, stream>>>(u, w_in, w, w_bias, out, hbuf);
}